// Round 13
// baseline (8659.399 us; speedup 1.0000x reference)
//
#include <hip/hip_runtime.h>
#include <stdint.h>

// BDH: B=2 T=2048 D=256 H=4 N=32768 Nh=8192 L=6 VOCAB=256
typedef unsigned short u16;
typedef __bf16 bfv8 __attribute__((ext_vector_type(8)));
typedef float f32x4 __attribute__((ext_vector_type(4)));

#define BM 128
#define BN 128
#define BK 64

__device__ __forceinline__ float b2f(u16 u){ union{float f; unsigned int i;} x; x.i = ((unsigned int)u)<<16; return x.f; }
__device__ __forceinline__ u16 f2b(float f){ union{float f; unsigned int i;} x; x.f = f; unsigned int r = x.i + 0x7fffu + ((x.i>>16)&1u); return (u16)(r>>16); }

__device__ __forceinline__ void load16_lds(const void* g, void* l){
  __builtin_amdgcn_global_load_lds(
      (const __attribute__((address_space(1))) void*)g,
      (__attribute__((address_space(3))) void*)l, 16, 0, 0);
}

// bijective XCD-aware block remap (m204), then decompose
__device__ __forceinline__ void swz(int& bx, int& by, int& bz){
  int gx = gridDim.x, gy = gridDim.y;
  int nw = gx*gy*gridDim.z;
  int flat = blockIdx.x + gx*(blockIdx.y + gy*blockIdx.z);
  int q = nw >> 3, r = nw & 7, xcd = flat & 7, i = flat >> 3;
  int wg = (xcd < r ? xcd*(q+1) : r*(q+1) + (xcd-r)*q) + i;
  bx = wg % gx; int t = wg / gx; by = t % gy; bz = t / gy;
}

struct GP {
  const u16* A; const u16* Bt; const u16* A2; const u16* Bt2;
  const u16* ct; const u16* st;
  float* Cf; u16* Cb; u16* Y;
  int bh0, zs, zm;
};

// BK=64 2-stage double-buffered K-loop (128B segments, vmcnt(8)) — R12 proven
template<int LDA, int LDB, bool PAIRB>
__device__ __forceinline__ void kloop(const u16* A, const u16* Bt, int m0, int n0,
                                      int kbeg, int kend,
                                      u16 (&As)[2][8192], u16 (&Bs)[2][8192],
                                      f32x4 (&acc)[4][4]){
  const int tid = threadIdx.x;
  const int lane = tid & 63;
  const int wid = tid >> 6;
  const int wm = wid >> 1, wn = wid & 1;
  const int rr = tid >> 3;
  const int slot = tid & 7;
  const int nt = (kend - kbeg) / BK;
  if (nt <= 0) return;

  auto stage = [&](int k0, int buf){
    #pragma unroll
    for (int q = 0; q < 4; ++q){
      int row = q*32 + rr;
      int ks = slot ^ (row & 7);
      load16_lds(A + (long)(m0 + row)*LDA + (k0 + ks*8), &As[buf][q*2048 + wid*512]);
    }
    #pragma unroll
    for (int q = 0; q < 4; ++q){
      int row = q*32 + rr;
      int ks = slot ^ (row & 7);
      long brow;
      if (PAIRB){ int wnb = row >> 6, sub = (row >> 5) & 1, r5 = row & 31;
                  brow = n0 + wnb*32 + r5 + sub*4096; }
      else brow = n0 + row;
      load16_lds(Bt + brow*(long)LDB + (k0 + ks*8), &Bs[buf][q*2048 + wid*512]);
    }
  };
  auto compute = [&](int buf){
    const int r16 = lane & 15, s4 = lane >> 4;
    #pragma unroll
    for (int kk = 0; kk < 2; ++kk){
      bfv8 af[4], bf[4];
      #pragma unroll
      for (int i = 0; i < 4; ++i){
        int ar = wm*64 + i*16 + r16;
        af[i] = *(const bfv8*)(&As[buf][ar*64 + (((kk*4 + s4) ^ (ar & 7))*8)]);
        int br = wn*64 + i*16 + r16;
        bf[i] = *(const bfv8*)(&Bs[buf][br*64 + (((kk*4 + s4) ^ (br & 7))*8)]);
      }
      #pragma unroll
      for (int i = 0; i < 4; ++i)
        #pragma unroll
        for (int j = 0; j < 4; ++j)
          acc[i][j] = __builtin_amdgcn_mfma_f32_16x16x32_bf16(af[i], bf[j], acc[i][j], 0,0,0);
    }
  };

  stage(kbeg, 0);
  int cur = 0;
  for (int t = 0; t < nt-1; ++t){
    stage(kbeg + (t+1)*BK, cur^1);
    asm volatile("s_waitcnt vmcnt(8)" ::: "memory");
    __builtin_amdgcn_s_barrier();
    compute(cur);
    asm volatile("s_waitcnt lgkmcnt(0)" ::: "memory");
    __builtin_amdgcn_s_barrier();
    cur ^= 1;
  }
  asm volatile("s_waitcnt vmcnt(0)" ::: "memory");
  __builtin_amdgcn_s_barrier();
  compute(cur);
  asm volatile("s_waitcnt lgkmcnt(0)" ::: "memory");
  __builtin_amdgcn_s_barrier();
}

// 256x256 tile loop, BK=32, 512 threads (8 waves 2Mx4N) — R11 proven form.
// PAIR=1: B rows 0..127 = n0+r (low cols), 128..255 = n0+4096+r (high cols)
template<int LDA, int LDB, int PAIR>
__device__ __forceinline__ void kloop256(const u16* A, const u16* Bt, int m0, int n0,
                                         int kbeg, int kend,
                                         u16 (&As)[2][8192], u16 (&Bs)[2][8192],
                                         f32x4 (&acc)[8][4]){
  const int tid = threadIdx.x;          // 0..511
  const int lane = tid & 63;
  const int wid = tid >> 6;             // 0..7
  const int srow = tid >> 2;            // 0..127
  const int sslot = tid & 3;
  const int nt = (kend - kbeg) / 32;
  if (nt <= 0) return;

  auto stage = [&](int k0, int buf){
    #pragma unroll
    for (int q = 0; q < 2; ++q){
      int row = q*128 + srow;           // 0..255
      int ks = sslot ^ ((row >> 1) & 3);
      load16_lds(A + (long)(m0 + row)*LDA + (k0 + ks*8), &As[buf][q*4096 + wid*512]);
    }
    #pragma unroll
    for (int q = 0; q < 2; ++q){
      int row = q*128 + srow;
      int ks = sslot ^ ((row >> 1) & 3);
      long brow;
      if (PAIR) brow = n0 + (row & 127) + (long)(row >> 7)*4096;
      else      brow = n0 + row;
      load16_lds(Bt + brow*(long)LDB + (k0 + ks*8), &Bs[buf][q*4096 + wid*512]);
    }
  };
  auto compute = [&](int buf){
    const int wm = wid >> 2, wn = wid & 3;
    const int r16 = lane & 15, s4 = lane >> 4;
    bfv8 af[8], bf[4];
    #pragma unroll
    for (int i = 0; i < 8; ++i){
      int ar = wm*128 + i*16 + r16;
      af[i] = *(const bfv8*)(&As[buf][ar*32 + ((s4 ^ ((ar>>1)&3))*8)]);
    }
    #pragma unroll
    for (int j = 0; j < 4; ++j){
      int br;
      if (PAIR) br = (j < 2) ? (wn*32 + j*16 + r16) : (128 + wn*32 + (j-2)*16 + r16);
      else      br = wn*64 + j*16 + r16;
      bf[j] = *(const bfv8*)(&Bs[buf][br*32 + ((s4 ^ ((br>>1)&3))*8)]);
    }
    #pragma unroll
    for (int i = 0; i < 8; ++i)
      #pragma unroll
      for (int j = 0; j < 4; ++j)
        acc[i][j] = __builtin_amdgcn_mfma_f32_16x16x32_bf16(af[i], bf[j], acc[i][j], 0,0,0);
  };

  stage(kbeg, 0);
  int cur = 0;
  for (int t = 0; t < nt-1; ++t){
    stage(kbeg + (t+1)*32, cur^1);
    asm volatile("s_waitcnt vmcnt(4)" ::: "memory");
    __builtin_amdgcn_s_barrier();
    compute(cur);
    asm volatile("s_waitcnt lgkmcnt(0)" ::: "memory");
    __builtin_amdgcn_s_barrier();
    cur ^= 1;
  }
  asm volatile("s_waitcnt vmcnt(0)" ::: "memory");
  __builtin_amdgcn_s_barrier();
  compute(cur);
  asm volatile("s_waitcnt lgkmcnt(0)" ::: "memory");
  __builtin_amdgcn_s_barrier();
}

#define EPI_SETUP const int lane = threadIdx.x & 63, wid = threadIdx.x >> 6; \
  const int wm = wid >> 1, wn = wid & 1; const int r16 = lane & 15, s4 = lane >> 4;
#define EPI_SETUP8 const int lane = threadIdx.x & 63, wid = threadIdx.x >> 6; \
  const int wm = wid >> 2, wn = wid & 3; const int r16 = lane & 15, s4 = lane >> 4;

// G1+rope 256-tile (R11 proven): xr = rope(relu(v @ dx_h)) -> Cb[z]
__global__ __launch_bounds__(512) void g_rope(GP p){
  int bx, by, bz; swz(bx, by, bz);
  const int m0 = by*256, n0 = bx*128, z = bz;
  const int bh = p.bh0 + z, b = bh >> 2, h = bh & 3;
  __shared__ u16 As[2][8192], Bs[2][8192];
  f32x4 acc[8][4] = {};
  kloop256<256,256,1>(p.A + (long)b*524288, p.Bt + (long)h*2097152, m0, n0, 0, 256, As, Bs, acc);
  EPI_SETUP8
  #pragma unroll
  for (int i = 0; i < 8; ++i)
    #pragma unroll
    for (int j = 0; j < 2; ++j){
      int cl = n0 + wn*32 + j*16 + r16;
      #pragma unroll
      for (int v = 0; v < 4; ++v){
        int row = m0 + wm*128 + i*16 + s4*4 + v;
        float x1 = fmaxf(acc[i][j][v], 0.f);
        float x2 = fmaxf(acc[i][j+2][v], 0.f);
        float c = b2f(p.ct[(long)row*4096 + cl]);
        float s = b2f(p.st[(long)row*4096 + cl]);
        p.Cb[(long)z*16777216 + (long)row*8192 + cl]        = f2b(x1*c - x2*s);
        p.Cb[(long)z*16777216 + (long)row*8192 + cl + 4096] = f2b(x2*c + x1*s);
      }
    }
}

// QK (R12 proven): sc[z] = causal_mask(xr[z] @ xr[z]^T), 128x128, live iff n0 <= m0
__global__ __launch_bounds__(256) void g_qk(GP p){
  int bx, by, bz; swz(bx, by, bz);
  const int m0 = by*BM, n0 = bx*BN, z = bz;
  if (n0 >= m0 + BM) return;
  __shared__ u16 As[2][8192], Bs[2][8192];
  f32x4 acc[4][4] = {};
  const u16* A = p.A + (long)z*16777216;
  kloop<8192,8192,false>(A, A, m0, n0, 0, 8192, As, Bs, acc);
  EPI_SETUP
  u16* C = p.Cb + (long)z*4194304;
  #pragma unroll
  for (int i = 0; i < 4; ++i)
    #pragma unroll
    for (int j = 0; j < 4; ++j){
      int col = n0 + wn*64 + j*16 + r16;
      #pragma unroll
      for (int v = 0; v < 4; ++v){
        int row = m0 + wm*64 + i*16 + s4*4 + v;
        C[(long)row*2048 + col] = f2b(row > col ? acc[i][j][v] : 0.f);
      }
    }
}

// PV split-K (R12 proven)
__global__ __launch_bounds__(256) void g_pv(GP p){
  int bx, by, bz; swz(bx, by, bz);
  const int m0 = by*BM, n0 = bx*BN;
  const int head = bz >> p.zs, sl = bz & p.zm;
  const int b = (p.bh0 + head) >> 2;
  const int kc = 2048 >> p.zs;
  const int kbeg = sl*kc;
  const int kend = min(min(2048, m0 + BM), kbeg + kc);
  __shared__ u16 As[2][8192], Bs[2][8192];
  f32x4 acc[4][4] = {};
  kloop<2048,2048,false>(p.A + (long)head*4194304, p.Bt + (long)b*524288, m0, n0, kbeg, kend, As, Bs, acc);
  EPI_SETUP
  #pragma unroll
  for (int i = 0; i < 4; ++i)
    #pragma unroll
    for (int j = 0; j < 4; ++j){
      int col = n0 + wn*64 + j*16 + r16;
      #pragma unroll
      for (int v = 0; v < 4; ++v){
        int row = m0 + wm*64 + i*16 + s4*4 + v;
        p.Cf[(long)bz*524288 + (long)row*256 + col] = acc[i][j][v];
      }
    }
}

// fused y 256-tile two-pass: Y[z] = relu(lnA[z] @ dyT_h) * relu(v[b] @ dxT_h)
// pass1 acc packed to bf16 stash (64 VGPR), acc reused for pass2.
__global__ __launch_bounds__(512) void g_fuse(GP p){
  int bx, by, bz; swz(bx, by, bz);
  const int m0 = by*256, n0 = bx*256, z = bz;
  const int bh = p.bh0 + z, b = bh >> 2, h = bh & 3;
  __shared__ u16 As[2][8192], Bs[2][8192];
  f32x4 acc[8][4] = {};
  kloop256<256,256,0>(p.A + (long)z*524288, p.Bt + (long)h*2097152, m0, n0, 0, 256, As, Bs, acc);
  unsigned stash[8][4][2];
  #pragma unroll
  for (int i = 0; i < 8; ++i)
    #pragma unroll
    for (int j = 0; j < 4; ++j){
      stash[i][j][0] = (unsigned)f2b(fmaxf(acc[i][j][0],0.f)) | ((unsigned)f2b(fmaxf(acc[i][j][1],0.f)) << 16);
      stash[i][j][1] = (unsigned)f2b(fmaxf(acc[i][j][2],0.f)) | ((unsigned)f2b(fmaxf(acc[i][j][3],0.f)) << 16);
      acc[i][j] = f32x4{0.f,0.f,0.f,0.f};
    }
  kloop256<256,256,0>(p.A2 + (long)b*524288, p.Bt2 + (long)h*2097152, m0, n0, 0, 256, As, Bs, acc);
  EPI_SETUP8
  #pragma unroll
  for (int i = 0; i < 8; ++i)
    #pragma unroll
    for (int j = 0; j < 4; ++j){
      int col = n0 + wn*64 + j*16 + r16;
      #pragma unroll
      for (int v = 0; v < 4; ++v){
        int row = m0 + wm*128 + i*16 + s4*4 + v;
        float y1 = b2f((u16)((stash[i][j][v>>1] >> ((v&1)*16)) & 0xffffu));
        p.Y[(long)z*16777216 + (long)row*8192 + col] =
            f2b(fmaxf(acc[i][j][v], 0.f) * y1);
      }
    }
}

// G3 split-K (R12 proven)
__global__ __launch_bounds__(256) void g_enc(GP p){
  int bx, by, bz; swz(bx, by, bz);
  const int m0 = by*BM, n0 = bx*BN;
  const int head = bz >> p.zs, sp = bz & p.zm;
  const int h = (p.bh0 + head) & 3;
  const int kc = 8192 >> p.zs;
  const int kbeg = sp*kc, kend = kbeg + kc;
  __shared__ u16 As[2][8192], Bs[2][8192];
  f32x4 acc[4][4] = {};
  kloop<8192,32768,false>(p.A + (long)head*16777216, p.Bt + (long)h*8192, m0, n0, kbeg, kend, As, Bs, acc);
  EPI_SETUP
  #pragma unroll
  for (int i = 0; i < 4; ++i)
    #pragma unroll
    for (int j = 0; j < 4; ++j){
      int col = n0 + wn*64 + j*16 + r16;
      #pragma unroll
      for (int v = 0; v < 4; ++v){
        int row = m0 + wm*64 + i*16 + s4*4 + v;
        p.Cf[(long)bz*524288 + (long)row*256 + col] = acc[i][j][v];
      }
    }
}

// readout (R12 proven)
__global__ __launch_bounds__(256) void g_out(GP p){
  int bx, by, bz; swz(bx, by, bz); (void)bz;
  const int m0 = by*BM, n0 = bx*BN;
  __shared__ u16 As[2][8192], Bs[2][8192];
  f32x4 acc[4][4] = {};
  kloop<256,256,false>(p.A, p.Bt, m0, n0, 0, 256, As, Bs, acc);
  EPI_SETUP
  #pragma unroll
  for (int i = 0; i < 4; ++i)
    #pragma unroll
    for (int j = 0; j < 4; ++j){
      int col = n0 + wn*64 + j*16 + r16;
      #pragma unroll
      for (int v = 0; v < 4; ++v){
        int row = m0 + wm*64 + i*16 + s4*4 + v;
        p.Cf[(long)row*256 + col] = acc[i][j][v];
      }
    }
}

// ---------------- small kernels ----------------

__device__ __forceinline__ float wave_sum(float v){
  #pragma unroll
  for (int o = 32; o > 0; o >>= 1) v += __shfl_down(v, o, 64);
  return v;
}
__device__ __forceinline__ float block_sum(float v, float* sm){
  v = wave_sum(v);
  __syncthreads();
  if ((threadIdx.x & 63) == 0) sm[threadIdx.x >> 6] = v;
  __syncthreads();
  return sm[0] + sm[1] + sm[2] + sm[3];
}

// bf16 state: writes vbf + vbt only
__global__ __launch_bounds__(256) void k_embed(const int* idx, const float* wte,
                                               u16* vbf, u16* vbt){
  __shared__ float sm[4];
  __shared__ int is64_s;
  int row = blockIdx.x, d = threadIdx.x;
  int oddnz = (d < 64) ? (idx[2*d + 1] != 0) : 0;     // int64 vs int32 probe
  unsigned long long mb = __ballot(oddnz);
  if (threadIdx.x == 0) is64_s = (mb == 0ULL);
  __syncthreads();
  int tok = is64_s ? idx[2*row] : idx[row];
  float x = wte[tok*256 + d];
  float m = block_sum(x, sm) * (1.f/256.f);
  float dd = x - m;
  float var = block_sum(dd*dd, sm) * (1.f/256.f);
  float y = dd * rsqrtf(var + 1e-5f);
  vbf[(long)row*256 + d] = f2b(y);
  int b = row >> 11, t = row & 2047;
  vbt[((long)(b*256 + d))*2048 + t] = f2b(y);
}

// sum pv slices of abuf, LN -> lnA (bf16)
__global__ __launch_bounds__(256) void k_ln(const float* abuf, u16* out, int pv){
  __shared__ float sm[4];
  int row = blockIdx.x, d = threadIdx.x;
  int head = row >> 11, t = row & 2047;
  float x = 0.f;
  for (int s = 0; s < pv; ++s) x += abuf[((long)(head*pv + s) << 19) + (long)t*256 + d];
  float m = block_sum(x, sm) * (1.f/256.f);
  float dd = x - m;
  float var = block_sum(dd*dd, sm) * (1.f/256.f);
  out[(long)row*256 + d] = f2b(dd * rsqrtf(var + 1e-5f));
}

// t1[b] (init or +=) sum over this chunk's heads/splits of part
__global__ __launch_bounds__(256) void k_acc(const float* part, float* t1,
                                             int bh0, int gc, int ps){
  int t = blockIdx.x, d = threadIdx.x;
  long o = (long)t*256 + d;
  float s0 = 0.f, s1 = 0.f;
  for (int z = 0; z < gc; ++z){
    float v = 0.f;
    for (int sp = 0; sp < ps; ++sp) v += part[((long)(z*ps + sp) << 19) + o];
    if (((bh0 + z) >> 2) == 0) s0 += v; else s1 += v;
  }
  #pragma unroll
  for (int b = 0; b < 2; ++b){
    int lo = bh0 > 4*b ? bh0 : 4*b;
    int hi = (bh0 + gc) < (4*b + 4) ? (bh0 + gc) : (4*b + 4);
    if (lo < hi){
      float s = b == 0 ? s0 : s1;
      if (lo == 4*b) t1[((long)b << 19) + o] = s;
      else           t1[((long)b << 19) + o] += s;
    }
  }
}

// bf16 state: v = ln(v + ln(t1)); refresh bf16 copies
__global__ __launch_bounds__(256) void k_finish(const float* t1, u16* vbf, u16* vbt){
  __shared__ float sm[4];
  int row = blockIdx.x; int d = threadIdx.x;
  int b = row >> 11, t = row & 2047;
  float s = t1[(long)row*256 + d];
  float m = block_sum(s, sm) * (1.f/256.f);
  float dd = s - m;
  float var = block_sum(dd*dd, sm) * (1.f/256.f);
  float u = dd * rsqrtf(var + 1e-5f);
  float wv = b2f(vbf[(long)row*256 + d]) + u;
  float m2 = block_sum(wv, sm) * (1.f/256.f);
  float d2 = wv - m2;
  float v2 = block_sum(d2*d2, sm) * (1.f/256.f);
  float y = d2 * rsqrtf(v2 + 1e-5f);
  vbf[(long)row*256 + d] = f2b(y);
  vbt[((long)(b*256 + d))*2048 + t] = f2b(y);
}

__global__ __launch_bounds__(256) void k_cossin(u16* ct, u16* st){
  int tid = blockIdx.x*256 + threadIdx.x;     // 2048*4096
  int t = tid >> 12, i = tid & 4095;
  float f = powf(10000.0f, -(float)i * (1.0f/4096.0f));
  float a = (float)t * f;
  float s, c; sincosf(a, &s, &c);
  ct[tid] = f2b(c); st[tid] = f2b(s);
}

// out[c][r] = bf16(in[r][c]); grid (C/32, R/32, Z), block (32,8)
__global__ void k_transpose(const float* in, u16* out, int R, int C, long in_z, long out_z){
  __shared__ float tile[32][33];
  const float* I = in + (long)blockIdx.z * in_z;
  u16* O = out + (long)blockIdx.z * out_z;
  int c0 = blockIdx.x*32, r0 = blockIdx.y*32;
  int tx = threadIdx.x, ty = threadIdx.y;
  #pragma unroll
  for (int k = 0; k < 4; ++k){ int r = ty + k*8; tile[r][tx] = I[(long)(r0+r)*C + c0+tx]; }
  __syncthreads();
  #pragma unroll
  for (int k = 0; k < 4; ++k){ int r = ty + k*8; O[(long)(c0+r)*R + r0+tx] = f2b(tile[tx][r]); }
}

// ---------------- host ----------------

extern "C" void kernel_launch(void* const* d_in, const int* in_sizes, int n_in,
                              void* d_out, int out_size, void* d_ws, size_t ws_size,
                              hipStream_t stream){
  const int*   idx = (const int*)d_in[0];
  const float* wte = (const float*)d_in[1];
  const float* enc = (const float*)d_in[2];
  const float* dx  = (const float*)d_in[3];
  const float* dy  = (const float*)d_in[4];
  const float* ro  = (const float*)d_in[5];
  float* out = (float*)d_out;
  (void)in_sizes; (void)n_in; (void)out_size;

  // ladder: base 92,274,688 + gc*(xbuf 33,554,432 + scb 8,388,608 + abuf pv*2,097,152)
  int gc = 1, pv = 2;
  {
    const int gcs[4] = {4, 3, 2, 1};
    for (int i = 0; i < 4; ++i){
      int g = gcs[i]; int pvt = (g >= 4) ? 1 : 2;
      size_t need = 92274688UL + (size_t)g*(33554432UL + 8388608UL + (size_t)pvt*2097152UL);
      if (need <= ws_size){ gc = g; pv = pvt; break; }
    }
  }
  const int ps = 2;
  const int pvs = (pv == 2) ? 1 : 0;

  char* w = (char*)d_ws;
  size_t off = 0;
  auto alloc = [&](size_t b){ size_t r = off; off += (b + 255) & ~(size_t)255; return r; };
  u16*   v_bf  = (u16*)  (w + alloc(4096UL*256*2));
  u16*   v_bt  = (u16*)  (w + alloc(2UL*256*2048*2));
  u16*   dxT   = (u16*)  (w + alloc(4UL*8192*256*2));
  u16*   dyT   = (u16*)  (w + alloc(4UL*8192*256*2));
  u16*   encT  = (u16*)  (w + alloc(256UL*32768*2));
  u16*   ct    = (u16*)  (w + alloc(2048UL*4096*2));
  u16*   st    = (u16*)  (w + alloc(2048UL*4096*2));
  float* t1    = (float*)(w + alloc(2UL*2048*256*4));
  u16*   xbuf  = (u16*)  (w + alloc((size_t)gc*33554432));
  u16*   scb   = (u16*)  (w + alloc((size_t)gc*8388608));
  float* abuf  = (float*)(w + alloc((size_t)gc*pv*2097152UL));
  float* part  = (float*)scb;                                  // alias: sc dead after g_pv
  u16*   lnAb  = (u16*)((char*)scb + (size_t)gc*ps*2097152UL); // alias, after part region
  u16*   roT   = (u16*)t1;                                     // alias: t1 dead after layers

  dim3 tb(32, 8);
  k_cossin<<<32768, 256, 0, stream>>>(ct, st);
  k_transpose<<<dim3(256, 8, 4),  tb, 0, stream>>>(dx,  dxT,  256,   8192, 256L*8192, 8192L*256);
  k_transpose<<<dim3(256, 8, 4),  tb, 0, stream>>>(dy,  dyT,  256,   8192, 256L*8192, 8192L*256);
  k_transpose<<<dim3(8, 1024, 1), tb, 0, stream>>>(enc, encT, 32768, 256,  0, 0);
  k_embed<<<4096, 256, 0, stream>>>(idx, wte, v_bf, v_bt);

  for (int l = 0; l < 6; ++l){
    for (int bh0 = 0; bh0 < 8; bh0 += gc){
      int ze = (8 - bh0 < gc) ? (8 - bh0) : gc;
      { GP g{}; g.bh0=bh0; g.A=v_bf; g.Bt=dxT; g.ct=ct; g.st=st; g.Cb=xbuf;
        g_rope<<<dim3(32,8,ze), 512, 0, stream>>>(g); }
      { GP g{}; g.bh0=bh0; g.A=xbuf; g.Cb=scb;
        g_qk<<<dim3(16,16,ze), 256, 0, stream>>>(g); }
      { GP g{}; g.bh0=bh0; g.A=scb; g.Bt=v_bt; g.Cf=abuf; g.zs=pvs; g.zm=pv-1;
        g_pv<<<dim3(2,16,ze*pv), 256, 0, stream>>>(g); }
      k_ln<<<ze*2048, 256, 0, stream>>>(abuf, lnAb, pv);
      { GP g{}; g.bh0=bh0; g.A=lnAb; g.Bt=dyT; g.A2=v_bf; g.Bt2=dxT; g.Y=xbuf;
        g_fuse<<<dim3(32,8,ze), 512, 0, stream>>>(g); }
      { GP g{}; g.bh0=bh0; g.A=xbuf; g.Bt=encT; g.Cf=part; g.zs=1; g.zm=1;
        g_enc<<<dim3(2,16,ze*ps), 256, 0, stream>>>(g); }
      k_acc<<<2048, 256, 0, stream>>>(part, t1, bh0, ze, ps);
    }
    k_finish<<<4096, 256, 0, stream>>>(t1, v_bf, v_bt);
  }
  k_transpose<<<dim3(8, 8, 1), tb, 0, stream>>>(ro, roT, 256, 256, 0, 0);
  { GP g{}; g.A=v_bf; g.Bt=roT; g.Cf=out;
    g_out<<<dim3(2,32,1), 256, 0, stream>>>(g); }
}

// Round 14
// 7794.386 us; speedup vs baseline: 1.1110x; 1.1110x over previous
//
#include <hip/hip_runtime.h>
#include <stdint.h>

// BDH: B=2 T=2048 D=256 H=4 N=32768 Nh=8192 L=6 VOCAB=256
typedef unsigned short u16;
typedef __bf16 bfv8 __attribute__((ext_vector_type(8)));
typedef float f32x4 __attribute__((ext_vector_type(4)));

#define BM 128
#define BN 128
#define BK 64

__device__ __forceinline__ float b2f(u16 u){ union{float f; unsigned int i;} x; x.i = ((unsigned int)u)<<16; return x.f; }
__device__ __forceinline__ u16 f2b(float f){ union{float f; unsigned int i;} x; x.f = f; unsigned int r = x.i + 0x7fffu + ((x.i>>16)&1u); return (u16)(r>>16); }

__device__ __forceinline__ void load16_lds(const void* g, void* l){
  __builtin_amdgcn_global_load_lds(
      (const __attribute__((address_space(1))) void*)g,
      (__attribute__((address_space(3))) void*)l, 16, 0, 0);
}

// bijective XCD-aware block remap (m204), then decompose
__device__ __forceinline__ void swz(int& bx, int& by, int& bz){
  int gx = gridDim.x, gy = gridDim.y;
  int nw = gx*gy*gridDim.z;
  int flat = blockIdx.x + gx*(blockIdx.y + gy*blockIdx.z);
  int q = nw >> 3, r = nw & 7, xcd = flat & 7, i = flat >> 3;
  int wg = (xcd < r ? xcd*(q+1) : r*(q+1) + (xcd-r)*q) + i;
  bx = wg % gx; int t = wg / gx; by = t % gy; bz = t / gy;
}

struct GP {
  const u16* A; const u16* Bt; const u16* A2; const u16* Bt2;
  const u16* ct; const u16* st;
  float* Cf; u16* Cb; u16* Y;
  int bh0, zs, zm;
};

// BK=64 2-stage double-buffered K-loop (128B segments, vmcnt(8)) — R12 proven
template<int LDA, int LDB, bool PAIRB>
__device__ __forceinline__ void kloop(const u16* A, const u16* Bt, int m0, int n0,
                                      int kbeg, int kend,
                                      u16 (&As)[2][8192], u16 (&Bs)[2][8192],
                                      f32x4 (&acc)[4][4]){
  const int tid = threadIdx.x;
  const int lane = tid & 63;
  const int wid = tid >> 6;
  const int wm = wid >> 1, wn = wid & 1;
  const int rr = tid >> 3;
  const int slot = tid & 7;
  const int nt = (kend - kbeg) / BK;
  if (nt <= 0) return;

  auto stage = [&](int k0, int buf){
    #pragma unroll
    for (int q = 0; q < 4; ++q){
      int row = q*32 + rr;
      int ks = slot ^ (row & 7);
      load16_lds(A + (long)(m0 + row)*LDA + (k0 + ks*8), &As[buf][q*2048 + wid*512]);
    }
    #pragma unroll
    for (int q = 0; q < 4; ++q){
      int row = q*32 + rr;
      int ks = slot ^ (row & 7);
      long brow;
      if (PAIRB){ int wnb = row >> 6, sub = (row >> 5) & 1, r5 = row & 31;
                  brow = n0 + wnb*32 + r5 + sub*4096; }
      else brow = n0 + row;
      load16_lds(Bt + brow*(long)LDB + (k0 + ks*8), &Bs[buf][q*2048 + wid*512]);
    }
  };
  auto compute = [&](int buf){
    const int r16 = lane & 15, s4 = lane >> 4;
    #pragma unroll
    for (int kk = 0; kk < 2; ++kk){
      bfv8 af[4], bf[4];
      #pragma unroll
      for (int i = 0; i < 4; ++i){
        int ar = wm*64 + i*16 + r16;
        af[i] = *(const bfv8*)(&As[buf][ar*64 + (((kk*4 + s4) ^ (ar & 7))*8)]);
        int br = wn*64 + i*16 + r16;
        bf[i] = *(const bfv8*)(&Bs[buf][br*64 + (((kk*4 + s4) ^ (br & 7))*8)]);
      }
      #pragma unroll
      for (int i = 0; i < 4; ++i)
        #pragma unroll
        for (int j = 0; j < 4; ++j)
          acc[i][j] = __builtin_amdgcn_mfma_f32_16x16x32_bf16(af[i], bf[j], acc[i][j], 0,0,0);
    }
  };

  stage(kbeg, 0);
  int cur = 0;
  for (int t = 0; t < nt-1; ++t){
    stage(kbeg + (t+1)*BK, cur^1);
    asm volatile("s_waitcnt vmcnt(8)" ::: "memory");
    __builtin_amdgcn_s_barrier();
    compute(cur);
    asm volatile("s_waitcnt lgkmcnt(0)" ::: "memory");
    __builtin_amdgcn_s_barrier();
    cur ^= 1;
  }
  asm volatile("s_waitcnt vmcnt(0)" ::: "memory");
  __builtin_amdgcn_s_barrier();
  compute(cur);
  asm volatile("s_waitcnt lgkmcnt(0)" ::: "memory");
  __builtin_amdgcn_s_barrier();
}

#define EPI_SETUP const int lane = threadIdx.x & 63, wid = threadIdx.x >> 6; \
  const int wm = wid >> 1, wn = wid & 1; const int r16 = lane & 15, s4 = lane >> 4;

// G1+rope (R12 proven): xr = rope(relu(v @ dx_h))  -> Cb[z] (2048 x 8192)
__global__ __launch_bounds__(256) void g_rope(GP p){
  int bx, by, bz; swz(bx, by, bz);
  const int m0 = by*BM, n0 = bx*64, z = bz;
  const int bh = p.bh0 + z, b = bh >> 2, h = bh & 3;
  __shared__ u16 As[2][8192], Bs[2][8192];
  f32x4 acc[4][4] = {};
  kloop<256,256,true>(p.A + (long)b*524288, p.Bt + (long)h*2097152, m0, n0, 0, 256, As, Bs, acc);
  EPI_SETUP
  #pragma unroll
  for (int i = 0; i < 4; ++i)
    #pragma unroll
    for (int j = 0; j < 2; ++j){
      int cl = n0 + wn*32 + j*16 + r16;
      #pragma unroll
      for (int v = 0; v < 4; ++v){
        int row = m0 + wm*64 + i*16 + s4*4 + v;
        float x1 = fmaxf(acc[i][j][v], 0.f);
        float x2 = fmaxf(acc[i][j+2][v], 0.f);
        float c = b2f(p.ct[(long)row*4096 + cl]);
        float s = b2f(p.st[(long)row*4096 + cl]);
        p.Cb[(long)z*16777216 + (long)row*8192 + cl]        = f2b(x1*c - x2*s);
        p.Cb[(long)z*16777216 + (long)row*8192 + cl + 4096] = f2b(x2*c + x1*s);
      }
    }
}

// QK 256x128 tiles, 512 threads (8 waves 4Mx2N), BK=64, LDS 96KB.
// sc[z] = causal_mask(xr[z] @ xr[z]^T); live iff n0 < m0+256 (72 tiles/head).
__global__ __launch_bounds__(512) void g_qk(GP p){
  int bx, by, bz; swz(bx, by, bz);
  const int m0 = by*256, n0 = bx*128, z = bz;
  if (n0 >= m0 + 256) return;
  const u16* A = p.A + (long)z*16777216;   // LDA = 8192
  __shared__ u16 As[2][16384], Bs[2][8192];
  const int tid = threadIdx.x, lane = tid & 63, wid = tid >> 6;
  const int wm = wid >> 1, wn = wid & 1;       // 4M x 2N waves
  const int rr = tid >> 3;                     // 0..63
  const int slot = tid & 7;
  f32x4 acc[4][4] = {};

  auto stage = [&](int k0, int buf){
    #pragma unroll
    for (int q = 0; q < 4; ++q){               // A: 256 rows
      int row = q*64 + rr;
      int ks = slot ^ (row & 7);
      load16_lds(A + (long)(m0 + row)*8192 + (k0 + ks*8), &As[buf][q*4096 + wid*512]);
    }
    #pragma unroll
    for (int q = 0; q < 2; ++q){               // B: 128 rows
      int row = q*64 + rr;
      int ks = slot ^ (row & 7);
      load16_lds(A + (long)(n0 + row)*8192 + (k0 + ks*8), &Bs[buf][q*4096 + wid*512]);
    }
  };
  auto compute = [&](int buf){
    const int r16 = lane & 15, s4 = lane >> 4;
    #pragma unroll
    for (int kk = 0; kk < 2; ++kk){
      bfv8 af[4], bf[4];
      #pragma unroll
      for (int i = 0; i < 4; ++i){
        int ar = wm*64 + i*16 + r16;           // 0..255
        af[i] = *(const bfv8*)(&As[buf][ar*64 + (((kk*4 + s4) ^ (ar & 7))*8)]);
        int br = wn*64 + i*16 + r16;           // 0..127
        bf[i] = *(const bfv8*)(&Bs[buf][br*64 + (((kk*4 + s4) ^ (br & 7))*8)]);
      }
      #pragma unroll
      for (int i = 0; i < 4; ++i)
        #pragma unroll
        for (int j = 0; j < 4; ++j)
          acc[i][j] = __builtin_amdgcn_mfma_f32_16x16x32_bf16(af[i], bf[j], acc[i][j], 0,0,0);
    }
  };

  const int nt = 128;                          // 8192/64
  stage(0, 0);
  int cur = 0;
  for (int t = 0; t < nt-1; ++t){
    stage((t+1)*BK, cur^1);
    asm volatile("s_waitcnt vmcnt(6)" ::: "memory");   // this tile's 6 landed
    __builtin_amdgcn_s_barrier();
    compute(cur);
    asm volatile("s_waitcnt lgkmcnt(0)" ::: "memory");
    __builtin_amdgcn_s_barrier();
    cur ^= 1;
  }
  asm volatile("s_waitcnt vmcnt(0)" ::: "memory");
  __builtin_amdgcn_s_barrier();
  compute(cur);

  u16* C = p.Cb + (long)z*4194304;
  const int r16 = lane & 15, s4 = lane >> 4;
  #pragma unroll
  for (int i = 0; i < 4; ++i)
    #pragma unroll
    for (int j = 0; j < 4; ++j){
      int col = n0 + wn*64 + j*16 + r16;
      #pragma unroll
      for (int v = 0; v < 4; ++v){
        int row = m0 + wm*64 + i*16 + s4*4 + v;
        C[(long)row*2048 + col] = f2b(row > col ? acc[i][j][v] : 0.f);
      }
    }
}

// PV split-K (R12 proven)
__global__ __launch_bounds__(256) void g_pv(GP p){
  int bx, by, bz; swz(bx, by, bz);
  const int m0 = by*BM, n0 = bx*BN;
  const int head = bz >> p.zs, sl = bz & p.zm;
  const int b = (p.bh0 + head) >> 2;
  const int kc = 2048 >> p.zs;
  const int kbeg = sl*kc;
  const int kend = min(min(2048, m0 + BM), kbeg + kc);
  __shared__ u16 As[2][8192], Bs[2][8192];
  f32x4 acc[4][4] = {};
  kloop<2048,2048,false>(p.A + (long)head*4194304, p.Bt + (long)b*524288, m0, n0, kbeg, kend, As, Bs, acc);
  EPI_SETUP
  #pragma unroll
  for (int i = 0; i < 4; ++i)
    #pragma unroll
    for (int j = 0; j < 4; ++j){
      int col = n0 + wn*64 + j*16 + r16;
      #pragma unroll
      for (int v = 0; v < 4; ++v){
        int row = m0 + wm*64 + i*16 + s4*4 + v;
        p.Cf[(long)bz*524288 + (long)row*256 + col] = acc[i][j][v];
      }
    }
}

// fused y (R12 proven): Y[z] = relu(lnA[z] @ dyT_h) * relu(v[b] @ dxT_h)
__global__ __launch_bounds__(256) void g_fuse(GP p){
  int bx, by, bz; swz(bx, by, bz);
  const int m0 = by*BM, n0 = bx*BN, z = bz;
  const int bh = p.bh0 + z, b = bh >> 2, h = bh & 3;
  __shared__ u16 As[2][8192], Bs[2][8192];
  f32x4 acc1[4][4] = {}, acc2[4][4] = {};
  kloop<256,256,false>(p.A  + (long)z*524288, p.Bt  + (long)h*2097152, m0, n0, 0, 256, As, Bs, acc1);
  kloop<256,256,false>(p.A2 + (long)b*524288, p.Bt2 + (long)h*2097152, m0, n0, 0, 256, As, Bs, acc2);
  EPI_SETUP
  #pragma unroll
  for (int i = 0; i < 4; ++i)
    #pragma unroll
    for (int j = 0; j < 4; ++j){
      int col = n0 + wn*64 + j*16 + r16;
      #pragma unroll
      for (int v = 0; v < 4; ++v){
        int row = m0 + wm*64 + i*16 + s4*4 + v;
        p.Y[(long)z*16777216 + (long)row*8192 + col] =
            f2b(fmaxf(acc1[i][j][v], 0.f) * fmaxf(acc2[i][j][v], 0.f));
      }
    }
}

// G3 split-K (R12 proven)
__global__ __launch_bounds__(256) void g_enc(GP p){
  int bx, by, bz; swz(bx, by, bz);
  const int m0 = by*BM, n0 = bx*BN;
  const int head = bz >> p.zs, sp = bz & p.zm;
  const int h = (p.bh0 + head) & 3;
  const int kc = 8192 >> p.zs;
  const int kbeg = sp*kc, kend = kbeg + kc;
  __shared__ u16 As[2][8192], Bs[2][8192];
  f32x4 acc[4][4] = {};
  kloop<8192,32768,false>(p.A + (long)head*16777216, p.Bt + (long)h*8192, m0, n0, kbeg, kend, As, Bs, acc);
  EPI_SETUP
  #pragma unroll
  for (int i = 0; i < 4; ++i)
    #pragma unroll
    for (int j = 0; j < 4; ++j){
      int col = n0 + wn*64 + j*16 + r16;
      #pragma unroll
      for (int v = 0; v < 4; ++v){
        int row = m0 + wm*64 + i*16 + s4*4 + v;
        p.Cf[(long)bz*524288 + (long)row*256 + col] = acc[i][j][v];
      }
    }
}

// readout (R12 proven)
__global__ __launch_bounds__(256) void g_out(GP p){
  int bx, by, bz; swz(bx, by, bz); (void)bz;
  const int m0 = by*BM, n0 = bx*BN;
  __shared__ u16 As[2][8192], Bs[2][8192];
  f32x4 acc[4][4] = {};
  kloop<256,256,false>(p.A, p.Bt, m0, n0, 0, 256, As, Bs, acc);
  EPI_SETUP
  #pragma unroll
  for (int i = 0; i < 4; ++i)
    #pragma unroll
    for (int j = 0; j < 4; ++j){
      int col = n0 + wn*64 + j*16 + r16;
      #pragma unroll
      for (int v = 0; v < 4; ++v){
        int row = m0 + wm*64 + i*16 + s4*4 + v;
        p.Cf[(long)row*256 + col] = acc[i][j][v];
      }
    }
}

// ---------------- small kernels ----------------

__device__ __forceinline__ float wave_sum(float v){
  #pragma unroll
  for (int o = 32; o > 0; o >>= 1) v += __shfl_down(v, o, 64);
  return v;
}
__device__ __forceinline__ float block_sum(float v, float* sm){
  v = wave_sum(v);
  __syncthreads();
  if ((threadIdx.x & 63) == 0) sm[threadIdx.x >> 6] = v;
  __syncthreads();
  return sm[0] + sm[1] + sm[2] + sm[3];
}

// bf16 state: writes vbf + vbt only
__global__ __launch_bounds__(256) void k_embed(const int* idx, const float* wte,
                                               u16* vbf, u16* vbt){
  __shared__ float sm[4];
  __shared__ int is64_s;
  int row = blockIdx.x, d = threadIdx.x;
  int oddnz = (d < 64) ? (idx[2*d + 1] != 0) : 0;     // int64 vs int32 probe
  unsigned long long mb = __ballot(oddnz);
  if (threadIdx.x == 0) is64_s = (mb == 0ULL);
  __syncthreads();
  int tok = is64_s ? idx[2*row] : idx[row];
  float x = wte[tok*256 + d];
  float m = block_sum(x, sm) * (1.f/256.f);
  float dd = x - m;
  float var = block_sum(dd*dd, sm) * (1.f/256.f);
  float y = dd * rsqrtf(var + 1e-5f);
  vbf[(long)row*256 + d] = f2b(y);
  int b = row >> 11, t = row & 2047;
  vbt[((long)(b*256 + d))*2048 + t] = f2b(y);
}

// sum pv slices of abuf, LN -> lnA (bf16)
__global__ __launch_bounds__(256) void k_ln(const float* abuf, u16* out, int pv){
  __shared__ float sm[4];
  int row = blockIdx.x, d = threadIdx.x;
  int head = row >> 11, t = row & 2047;
  float x = 0.f;
  for (int s = 0; s < pv; ++s) x += abuf[((long)(head*pv + s) << 19) + (long)t*256 + d];
  float m = block_sum(x, sm) * (1.f/256.f);
  float dd = x - m;
  float var = block_sum(dd*dd, sm) * (1.f/256.f);
  out[(long)row*256 + d] = f2b(dd * rsqrtf(var + 1e-5f));
}

// t1[b] (init or +=) sum over this chunk's heads/splits of part
__global__ __launch_bounds__(256) void k_acc(const float* part, float* t1,
                                             int bh0, int gc, int ps){
  int t = blockIdx.x, d = threadIdx.x;
  long o = (long)t*256 + d;
  float s0 = 0.f, s1 = 0.f;
  for (int z = 0; z < gc; ++z){
    float v = 0.f;
    for (int sp = 0; sp < ps; ++sp) v += part[((long)(z*ps + sp) << 19) + o];
    if (((bh0 + z) >> 2) == 0) s0 += v; else s1 += v;
  }
  #pragma unroll
  for (int b = 0; b < 2; ++b){
    int lo = bh0 > 4*b ? bh0 : 4*b;
    int hi = (bh0 + gc) < (4*b + 4) ? (bh0 + gc) : (4*b + 4);
    if (lo < hi){
      float s = b == 0 ? s0 : s1;
      if (lo == 4*b) t1[((long)b << 19) + o] = s;
      else           t1[((long)b << 19) + o] += s;
    }
  }
}

// bf16 state: v = ln(v + ln(t1)); refresh bf16 copies
__global__ __launch_bounds__(256) void k_finish(const float* t1, u16* vbf, u16* vbt){
  __shared__ float sm[4];
  int row = blockIdx.x; int d = threadIdx.x;
  int b = row >> 11, t = row & 2047;
  float s = t1[(long)row*256 + d];
  float m = block_sum(s, sm) * (1.f/256.f);
  float dd = s - m;
  float var = block_sum(dd*dd, sm) * (1.f/256.f);
  float u = dd * rsqrtf(var + 1e-5f);
  float wv = b2f(vbf[(long)row*256 + d]) + u;
  float m2 = block_sum(wv, sm) * (1.f/256.f);
  float d2 = wv - m2;
  float v2 = block_sum(d2*d2, sm) * (1.f/256.f);
  float y = d2 * rsqrtf(v2 + 1e-5f);
  vbf[(long)row*256 + d] = f2b(y);
  vbt[((long)(b*256 + d))*2048 + t] = f2b(y);
}

__global__ __launch_bounds__(256) void k_cossin(u16* ct, u16* st){
  int tid = blockIdx.x*256 + threadIdx.x;     // 2048*4096
  int t = tid >> 12, i = tid & 4095;
  float f = powf(10000.0f, -(float)i * (1.0f/4096.0f));
  float a = (float)t * f;
  float s, c; sincosf(a, &s, &c);
  ct[tid] = f2b(c); st[tid] = f2b(s);
}

// out[c][r] = bf16(in[r][c]); grid (C/32, R/32, Z), block (32,8)
__global__ void k_transpose(const float* in, u16* out, int R, int C, long in_z, long out_z){
  __shared__ float tile[32][33];
  const float* I = in + (long)blockIdx.z * in_z;
  u16* O = out + (long)blockIdx.z * out_z;
  int c0 = blockIdx.x*32, r0 = blockIdx.y*32;
  int tx = threadIdx.x, ty = threadIdx.y;
  #pragma unroll
  for (int k = 0; k < 4; ++k){ int r = ty + k*8; tile[r][tx] = I[(long)(r0+r)*C + c0+tx]; }
  __syncthreads();
  #pragma unroll
  for (int k = 0; k < 4; ++k){ int r = ty + k*8; O[(long)(c0+r)*R + r0+tx] = f2b(tile[tx][r]); }
}

// ---------------- host ----------------

extern "C" void kernel_launch(void* const* d_in, const int* in_sizes, int n_in,
                              void* d_out, int out_size, void* d_ws, size_t ws_size,
                              hipStream_t stream){
  const int*   idx = (const int*)d_in[0];
  const float* wte = (const float*)d_in[1];
  const float* enc = (const float*)d_in[2];
  const float* dx  = (const float*)d_in[3];
  const float* dy  = (const float*)d_in[4];
  const float* ro  = (const float*)d_in[5];
  float* out = (float*)d_out;
  (void)in_sizes; (void)n_in; (void)out_size;

  // ladder: base 92,274,688 + gc*(xbuf 33,554,432 + scb 8,388,608 + abuf pv*2,097,152)
  int gc = 1, pv = 2;
  {
    const int gcs[4] = {4, 3, 2, 1};
    for (int i = 0; i < 4; ++i){
      int g = gcs[i]; int pvt = (g >= 4) ? 1 : 2;
      size_t need = 92274688UL + (size_t)g*(33554432UL + 8388608UL + (size_t)pvt*2097152UL);
      if (need <= ws_size){ gc = g; pv = pvt; break; }
    }
  }
  const int ps = 2;
  const int pvs = (pv == 2) ? 1 : 0;

  char* w = (char*)d_ws;
  size_t off = 0;
  auto alloc = [&](size_t b){ size_t r = off; off += (b + 255) & ~(size_t)255; return r; };
  u16*   v_bf  = (u16*)  (w + alloc(4096UL*256*2));
  u16*   v_bt  = (u16*)  (w + alloc(2UL*256*2048*2));
  u16*   dxT   = (u16*)  (w + alloc(4UL*8192*256*2));
  u16*   dyT   = (u16*)  (w + alloc(4UL*8192*256*2));
  u16*   encT  = (u16*)  (w + alloc(256UL*32768*2));
  u16*   ct    = (u16*)  (w + alloc(2048UL*4096*2));
  u16*   st    = (u16*)  (w + alloc(2048UL*4096*2));
  float* t1    = (float*)(w + alloc(2UL*2048*256*4));
  u16*   xbuf  = (u16*)  (w + alloc((size_t)gc*33554432));
  u16*   scb   = (u16*)  (w + alloc((size_t)gc*8388608));
  float* abuf  = (float*)(w + alloc((size_t)gc*pv*2097152UL));
  float* part  = (float*)scb;                                  // alias: sc dead after g_pv
  u16*   lnAb  = (u16*)((char*)scb + (size_t)gc*ps*2097152UL); // alias, after part region
  u16*   roT   = (u16*)t1;                                     // alias: t1 dead after layers

  dim3 tb(32, 8);
  k_cossin<<<32768, 256, 0, stream>>>(ct, st);
  k_transpose<<<dim3(256, 8, 4),  tb, 0, stream>>>(dx,  dxT,  256,   8192, 256L*8192, 8192L*256);
  k_transpose<<<dim3(256, 8, 4),  tb, 0, stream>>>(dy,  dyT,  256,   8192, 256L*8192, 8192L*256);
  k_transpose<<<dim3(8, 1024, 1), tb, 0, stream>>>(enc, encT, 32768, 256,  0, 0);
  k_embed<<<4096, 256, 0, stream>>>(idx, wte, v_bf, v_bt);

  for (int l = 0; l < 6; ++l){
    for (int bh0 = 0; bh0 < 8; bh0 += gc){
      int ze = (8 - bh0 < gc) ? (8 - bh0) : gc;
      { GP g{}; g.bh0=bh0; g.A=v_bf; g.Bt=dxT; g.ct=ct; g.st=st; g.Cb=xbuf;
        g_rope<<<dim3(64,16,ze), 256, 0, stream>>>(g); }
      { GP g{}; g.bh0=bh0; g.A=xbuf; g.Cb=scb;
        g_qk<<<dim3(16,8,ze), 512, 0, stream>>>(g); }
      { GP g{}; g.bh0=bh0; g.A=scb; g.Bt=v_bt; g.Cf=abuf; g.zs=pvs; g.zm=pv-1;
        g_pv<<<dim3(2,16,ze*pv), 256, 0, stream>>>(g); }
      k_ln<<<ze*2048, 256, 0, stream>>>(abuf, lnAb, pv);
      { GP g{}; g.bh0=bh0; g.A=lnAb; g.Bt=dyT; g.A2=v_bf; g.Bt2=dxT; g.Y=xbuf;
        g_fuse<<<dim3(64,16,ze), 256, 0, stream>>>(g); }
      { GP g{}; g.bh0=bh0; g.A=xbuf; g.Bt=encT; g.Cf=part; g.zs=1; g.zm=1;
        g_enc<<<dim3(2,16,ze*ps), 256, 0, stream>>>(g); }
      k_acc<<<2048, 256, 0, stream>>>(part, t1, bh0, ze, ps);
    }
    k_finish<<<4096, 256, 0, stream>>>(t1, v_bf, v_bt);
  }
  k_transpose<<<dim3(8, 8, 1), tb, 0, stream>>>(ro, roT, 256, 256, 0, 0);
  { GP g{}; g.A=v_bf; g.Bt=roT; g.Cf=out;
    g_out<<<dim3(2,32,1), 256, 0, stream>>>(g); }
}

// Round 15
// 7518.513 us; speedup vs baseline: 1.1517x; 1.0367x over previous
//
#include <hip/hip_runtime.h>
#include <stdint.h>

// BDH: B=2 T=2048 D=256 H=4 N=32768 Nh=8192 L=6 VOCAB=256
typedef unsigned short u16;
typedef __bf16 bfv8 __attribute__((ext_vector_type(8)));
typedef float f32x4 __attribute__((ext_vector_type(4)));

#define BM 128
#define BN 128
#define BK 64

__device__ __forceinline__ float b2f(u16 u){ union{float f; unsigned int i;} x; x.i = ((unsigned int)u)<<16; return x.f; }
__device__ __forceinline__ u16 f2b(float f){ union{float f; unsigned int i;} x; x.f = f; unsigned int r = x.i + 0x7fffu + ((x.i>>16)&1u); return (u16)(r>>16); }

__device__ __forceinline__ void load16_lds(const void* g, void* l){
  __builtin_amdgcn_global_load_lds(
      (const __attribute__((address_space(1))) void*)g,
      (__attribute__((address_space(3))) void*)l, 16, 0, 0);
}

// bijective XCD-aware block remap (m204), then decompose
__device__ __forceinline__ void swz(int& bx, int& by, int& bz){
  int gx = gridDim.x, gy = gridDim.y;
  int nw = gx*gy*gridDim.z;
  int flat = blockIdx.x + gx*(blockIdx.y + gy*blockIdx.z);
  int q = nw >> 3, r = nw & 7, xcd = flat & 7, i = flat >> 3;
  int wg = (xcd < r ? xcd*(q+1) : r*(q+1) + (xcd-r)*q) + i;
  bx = wg % gx; int t = wg / gx; by = t % gy; bz = t / gy;
}

struct GP {
  const u16* A; const u16* Bt; const u16* A2; const u16* Bt2;
  const u16* ct; const u16* st;
  float* Cf; u16* Cb; u16* Y;
  int bh0, zs, zm;
};

// BK=64 2-stage double-buffered K-loop (128B segments, vmcnt(8)) — R12 proven
template<int LDA, int LDB, bool PAIRB>
__device__ __forceinline__ void kloop(const u16* A, const u16* Bt, int m0, int n0,
                                      int kbeg, int kend,
                                      u16 (&As)[2][8192], u16 (&Bs)[2][8192],
                                      f32x4 (&acc)[4][4]){
  const int tid = threadIdx.x;
  const int lane = tid & 63;
  const int wid = tid >> 6;
  const int wm = wid >> 1, wn = wid & 1;
  const int rr = tid >> 3;
  const int slot = tid & 7;
  const int nt = (kend - kbeg) / BK;
  if (nt <= 0) return;

  auto stage = [&](int k0, int buf){
    #pragma unroll
    for (int q = 0; q < 4; ++q){
      int row = q*32 + rr;
      int ks = slot ^ (row & 7);
      load16_lds(A + (long)(m0 + row)*LDA + (k0 + ks*8), &As[buf][q*2048 + wid*512]);
    }
    #pragma unroll
    for (int q = 0; q < 4; ++q){
      int row = q*32 + rr;
      int ks = slot ^ (row & 7);
      long brow;
      if (PAIRB){ int wnb = row >> 6, sub = (row >> 5) & 1, r5 = row & 31;
                  brow = n0 + wnb*32 + r5 + sub*4096; }
      else brow = n0 + row;
      load16_lds(Bt + brow*(long)LDB + (k0 + ks*8), &Bs[buf][q*2048 + wid*512]);
    }
  };
  auto compute = [&](int buf){
    const int r16 = lane & 15, s4 = lane >> 4;
    #pragma unroll
    for (int kk = 0; kk < 2; ++kk){
      bfv8 af[4], bf[4];
      #pragma unroll
      for (int i = 0; i < 4; ++i){
        int ar = wm*64 + i*16 + r16;
        af[i] = *(const bfv8*)(&As[buf][ar*64 + (((kk*4 + s4) ^ (ar & 7))*8)]);
        int br = wn*64 + i*16 + r16;
        bf[i] = *(const bfv8*)(&Bs[buf][br*64 + (((kk*4 + s4) ^ (br & 7))*8)]);
      }
      #pragma unroll
      for (int i = 0; i < 4; ++i)
        #pragma unroll
        for (int j = 0; j < 4; ++j)
          acc[i][j] = __builtin_amdgcn_mfma_f32_16x16x32_bf16(af[i], bf[j], acc[i][j], 0,0,0);
    }
  };

  stage(kbeg, 0);
  int cur = 0;
  for (int t = 0; t < nt-1; ++t){
    stage(kbeg + (t+1)*BK, cur^1);
    asm volatile("s_waitcnt vmcnt(8)" ::: "memory");
    __builtin_amdgcn_s_barrier();
    compute(cur);
    asm volatile("s_waitcnt lgkmcnt(0)" ::: "memory");
    __builtin_amdgcn_s_barrier();
    cur ^= 1;
  }
  asm volatile("s_waitcnt vmcnt(0)" ::: "memory");
  __builtin_amdgcn_s_barrier();
  compute(cur);
  asm volatile("s_waitcnt lgkmcnt(0)" ::: "memory");
  __builtin_amdgcn_s_barrier();
}

#define EPI_SETUP const int lane = threadIdx.x & 63, wid = threadIdx.x >> 6; \
  const int wm = wid >> 1, wn = wid & 1; const int r16 = lane & 15, s4 = lane >> 4;

// G1+rope (R12 proven): xr = rope(relu(v @ dx_h))  -> Cb[z] (2048 x 8192)
__global__ __launch_bounds__(256) void g_rope(GP p){
  int bx, by, bz; swz(bx, by, bz);
  const int m0 = by*BM, n0 = bx*64, z = bz;
  const int bh = p.bh0 + z, b = bh >> 2, h = bh & 3;
  __shared__ u16 As[2][8192], Bs[2][8192];
  f32x4 acc[4][4] = {};
  kloop<256,256,true>(p.A + (long)b*524288, p.Bt + (long)h*2097152, m0, n0, 0, 256, As, Bs, acc);
  EPI_SETUP
  #pragma unroll
  for (int i = 0; i < 4; ++i)
    #pragma unroll
    for (int j = 0; j < 2; ++j){
      int cl = n0 + wn*32 + j*16 + r16;
      #pragma unroll
      for (int v = 0; v < 4; ++v){
        int row = m0 + wm*64 + i*16 + s4*4 + v;
        float x1 = fmaxf(acc[i][j][v], 0.f);
        float x2 = fmaxf(acc[i][j+2][v], 0.f);
        float c = b2f(p.ct[(long)row*4096 + cl]);
        float s = b2f(p.st[(long)row*4096 + cl]);
        p.Cb[(long)z*16777216 + (long)row*8192 + cl]        = f2b(x1*c - x2*s);
        p.Cb[(long)z*16777216 + (long)row*8192 + cl + 4096] = f2b(x2*c + x1*s);
      }
    }
}

// QK (R12 proven): sc[z] = causal_mask(xr[z] @ xr[z]^T), 128x128, live iff n0 <= m0
__global__ __launch_bounds__(256) void g_qk(GP p){
  int bx, by, bz; swz(bx, by, bz);
  const int m0 = by*BM, n0 = bx*BN, z = bz;
  if (n0 >= m0 + BM) return;
  __shared__ u16 As[2][8192], Bs[2][8192];
  f32x4 acc[4][4] = {};
  const u16* A = p.A + (long)z*16777216;
  kloop<8192,8192,false>(A, A, m0, n0, 0, 8192, As, Bs, acc);
  EPI_SETUP
  u16* C = p.Cb + (long)z*4194304;
  #pragma unroll
  for (int i = 0; i < 4; ++i)
    #pragma unroll
    for (int j = 0; j < 4; ++j){
      int col = n0 + wn*64 + j*16 + r16;
      #pragma unroll
      for (int v = 0; v < 4; ++v){
        int row = m0 + wm*64 + i*16 + s4*4 + v;
        C[(long)row*2048 + col] = f2b(row > col ? acc[i][j][v] : 0.f);
      }
    }
}

// PV split-K (R12 proven)
__global__ __launch_bounds__(256) void g_pv(GP p){
  int bx, by, bz; swz(bx, by, bz);
  const int m0 = by*BM, n0 = bx*BN;
  const int head = bz >> p.zs, sl = bz & p.zm;
  const int b = (p.bh0 + head) >> 2;
  const int kc = 2048 >> p.zs;
  const int kbeg = sl*kc;
  const int kend = min(min(2048, m0 + BM), kbeg + kc);
  __shared__ u16 As[2][8192], Bs[2][8192];
  f32x4 acc[4][4] = {};
  kloop<2048,2048,false>(p.A + (long)head*4194304, p.Bt + (long)b*524288, m0, n0, kbeg, kend, As, Bs, acc);
  EPI_SETUP
  #pragma unroll
  for (int i = 0; i < 4; ++i)
    #pragma unroll
    for (int j = 0; j < 4; ++j){
      int col = n0 + wn*64 + j*16 + r16;
      #pragma unroll
      for (int v = 0; v < 4; ++v){
        int row = m0 + wm*64 + i*16 + s4*4 + v;
        p.Cf[(long)bz*524288 + (long)row*256 + col] = acc[i][j][v];
      }
    }
}

// fused y (R12 proven): Y[z] = relu(lnA[z] @ dyT_h) * relu(v[b] @ dxT_h)
__global__ __launch_bounds__(256) void g_fuse(GP p){
  int bx, by, bz; swz(bx, by, bz);
  const int m0 = by*BM, n0 = bx*BN, z = bz;
  const int bh = p.bh0 + z, b = bh >> 2, h = bh & 3;
  __shared__ u16 As[2][8192], Bs[2][8192];
  f32x4 acc1[4][4] = {}, acc2[4][4] = {};
  kloop<256,256,false>(p.A  + (long)z*524288, p.Bt  + (long)h*2097152, m0, n0, 0, 256, As, Bs, acc1);
  kloop<256,256,false>(p.A2 + (long)b*524288, p.Bt2 + (long)h*2097152, m0, n0, 0, 256, As, Bs, acc2);
  EPI_SETUP
  #pragma unroll
  for (int i = 0; i < 4; ++i)
    #pragma unroll
    for (int j = 0; j < 4; ++j){
      int col = n0 + wn*64 + j*16 + r16;
      #pragma unroll
      for (int v = 0; v < 4; ++v){
        int row = m0 + wm*64 + i*16 + s4*4 + v;
        p.Y[(long)z*16777216 + (long)row*8192 + col] =
            f2b(fmaxf(acc1[i][j][v], 0.f) * fmaxf(acc2[i][j][v], 0.f));
      }
    }
}

// G3 split-K (R12 proven)
__global__ __launch_bounds__(256) void g_enc(GP p){
  int bx, by, bz; swz(bx, by, bz);
  const int m0 = by*BM, n0 = bx*BN;
  const int head = bz >> p.zs, sp = bz & p.zm;
  const int h = (p.bh0 + head) & 3;
  const int kc = 8192 >> p.zs;
  const int kbeg = sp*kc, kend = kbeg + kc;
  __shared__ u16 As[2][8192], Bs[2][8192];
  f32x4 acc[4][4] = {};
  kloop<8192,32768,false>(p.A + (long)head*16777216, p.Bt + (long)h*8192, m0, n0, kbeg, kend, As, Bs, acc);
  EPI_SETUP
  #pragma unroll
  for (int i = 0; i < 4; ++i)
    #pragma unroll
    for (int j = 0; j < 4; ++j){
      int col = n0 + wn*64 + j*16 + r16;
      #pragma unroll
      for (int v = 0; v < 4; ++v){
        int row = m0 + wm*64 + i*16 + s4*4 + v;
        p.Cf[(long)bz*524288 + (long)row*256 + col] = acc[i][j][v];
      }
    }
}

// readout (R12 proven)
__global__ __launch_bounds__(256) void g_out(GP p){
  int bx, by, bz; swz(bx, by, bz); (void)bz;
  const int m0 = by*BM, n0 = bx*BN;
  __shared__ u16 As[2][8192], Bs[2][8192];
  f32x4 acc[4][4] = {};
  kloop<256,256,false>(p.A, p.Bt, m0, n0, 0, 256, As, Bs, acc);
  EPI_SETUP
  #pragma unroll
  for (int i = 0; i < 4; ++i)
    #pragma unroll
    for (int j = 0; j < 4; ++j){
      int col = n0 + wn*64 + j*16 + r16;
      #pragma unroll
      for (int v = 0; v < 4; ++v){
        int row = m0 + wm*64 + i*16 + s4*4 + v;
        p.Cf[(long)row*256 + col] = acc[i][j][v];
      }
    }
}

// ---------------- small kernels ----------------

__device__ __forceinline__ float wave_sum(float v){
  #pragma unroll
  for (int o = 32; o > 0; o >>= 1) v += __shfl_down(v, o, 64);
  return v;
}
__device__ __forceinline__ float block_sum(float v, float* sm){
  v = wave_sum(v);
  __syncthreads();
  if ((threadIdx.x & 63) == 0) sm[threadIdx.x >> 6] = v;
  __syncthreads();
  return sm[0] + sm[1] + sm[2] + sm[3];
}

// bf16 state: writes vbf + vbt only
__global__ __launch_bounds__(256) void k_embed(const int* idx, const float* wte,
                                               u16* vbf, u16* vbt){
  __shared__ float sm[4];
  __shared__ int is64_s;
  int row = blockIdx.x, d = threadIdx.x;
  int oddnz = (d < 64) ? (idx[2*d + 1] != 0) : 0;     // int64 vs int32 probe
  unsigned long long mb = __ballot(oddnz);
  if (threadIdx.x == 0) is64_s = (mb == 0ULL);
  __syncthreads();
  int tok = is64_s ? idx[2*row] : idx[row];
  float x = wte[tok*256 + d];
  float m = block_sum(x, sm) * (1.f/256.f);
  float dd = x - m;
  float var = block_sum(dd*dd, sm) * (1.f/256.f);
  float y = dd * rsqrtf(var + 1e-5f);
  vbf[(long)row*256 + d] = f2b(y);
  int b = row >> 11, t = row & 2047;
  vbt[((long)(b*256 + d))*2048 + t] = f2b(y);
}

// sum pv slices of abuf, LN -> lnA (bf16)
__global__ __launch_bounds__(256) void k_ln(const float* abuf, u16* out, int pv){
  __shared__ float sm[4];
  int row = blockIdx.x, d = threadIdx.x;
  int head = row >> 11, t = row & 2047;
  float x = 0.f;
  for (int s = 0; s < pv; ++s) x += abuf[((long)(head*pv + s) << 19) + (long)t*256 + d];
  float m = block_sum(x, sm) * (1.f/256.f);
  float dd = x - m;
  float var = block_sum(dd*dd, sm) * (1.f/256.f);
  out[(long)row*256 + d] = f2b(dd * rsqrtf(var + 1e-5f));
}

// t1[b] (init or +=) sum over this chunk's heads/splits of part
__global__ __launch_bounds__(256) void k_acc(const float* part, float* t1,
                                             int bh0, int gc, int ps){
  int t = blockIdx.x, d = threadIdx.x;
  long o = (long)t*256 + d;
  float s0 = 0.f, s1 = 0.f;
  for (int z = 0; z < gc; ++z){
    float v = 0.f;
    for (int sp = 0; sp < ps; ++sp) v += part[((long)(z*ps + sp) << 19) + o];
    if (((bh0 + z) >> 2) == 0) s0 += v; else s1 += v;
  }
  #pragma unroll
  for (int b = 0; b < 2; ++b){
    int lo = bh0 > 4*b ? bh0 : 4*b;
    int hi = (bh0 + gc) < (4*b + 4) ? (bh0 + gc) : (4*b + 4);
    if (lo < hi){
      float s = b == 0 ? s0 : s1;
      if (lo == 4*b) t1[((long)b << 19) + o] = s;
      else           t1[((long)b << 19) + o] += s;
    }
  }
}

// bf16 state: v = ln(v + ln(t1)); refresh bf16 copies
__global__ __launch_bounds__(256) void k_finish(const float* t1, u16* vbf, u16* vbt){
  __shared__ float sm[4];
  int row = blockIdx.x; int d = threadIdx.x;
  int b = row >> 11, t = row & 2047;
  float s = t1[(long)row*256 + d];
  float m = block_sum(s, sm) * (1.f/256.f);
  float dd = s - m;
  float var = block_sum(dd*dd, sm) * (1.f/256.f);
  float u = dd * rsqrtf(var + 1e-5f);
  float wv = b2f(vbf[(long)row*256 + d]) + u;
  float m2 = block_sum(wv, sm) * (1.f/256.f);
  float d2 = wv - m2;
  float v2 = block_sum(d2*d2, sm) * (1.f/256.f);
  float y = d2 * rsqrtf(v2 + 1e-5f);
  vbf[(long)row*256 + d] = f2b(y);
  vbt[((long)(b*256 + d))*2048 + t] = f2b(y);
}

__global__ __launch_bounds__(256) void k_cossin(u16* ct, u16* st){
  int tid = blockIdx.x*256 + threadIdx.x;     // 2048*4096
  int t = tid >> 12, i = tid & 4095;
  float f = powf(10000.0f, -(float)i * (1.0f/4096.0f));
  float a = (float)t * f;
  float s, c; sincosf(a, &s, &c);
  ct[tid] = f2b(c); st[tid] = f2b(s);
}

// out[c][r] = bf16(in[r][c]); grid (C/32, R/32, Z), block (32,8)
__global__ void k_transpose(const float* in, u16* out, int R, int C, long in_z, long out_z){
  __shared__ float tile[32][33];
  const float* I = in + (long)blockIdx.z * in_z;
  u16* O = out + (long)blockIdx.z * out_z;
  int c0 = blockIdx.x*32, r0 = blockIdx.y*32;
  int tx = threadIdx.x, ty = threadIdx.y;
  #pragma unroll
  for (int k = 0; k < 4; ++k){ int r = ty + k*8; tile[r][tx] = I[(long)(r0+r)*C + c0+tx]; }
  __syncthreads();
  #pragma unroll
  for (int k = 0; k < 4; ++k){ int r = ty + k*8; O[(long)(c0+r)*R + r0+tx] = f2b(tile[tx][r]); }
}

// ---------------- host ----------------

extern "C" void kernel_launch(void* const* d_in, const int* in_sizes, int n_in,
                              void* d_out, int out_size, void* d_ws, size_t ws_size,
                              hipStream_t stream){
  const int*   idx = (const int*)d_in[0];
  const float* wte = (const float*)d_in[1];
  const float* enc = (const float*)d_in[2];
  const float* dx  = (const float*)d_in[3];
  const float* dy  = (const float*)d_in[4];
  const float* ro  = (const float*)d_in[5];
  float* out = (float*)d_out;
  (void)in_sizes; (void)n_in; (void)out_size;

  // ladder: base 92,274,688 + gc*(xbuf 33,554,432 + scb 8,388,608 + abuf pv*2,097,152)
  int gc = 1, pv = 2;
  {
    const int gcs[4] = {4, 3, 2, 1};
    for (int i = 0; i < 4; ++i){
      int g = gcs[i]; int pvt = (g >= 4) ? 1 : 2;
      size_t need = 92274688UL + (size_t)g*(33554432UL + 8388608UL + (size_t)pvt*2097152UL);
      if (need <= ws_size){ gc = g; pv = pvt; break; }
    }
  }
  const int ps = 2;
  const int pvs = (pv == 2) ? 1 : 0;

  char* w = (char*)d_ws;
  size_t off = 0;
  auto alloc = [&](size_t b){ size_t r = off; off += (b + 255) & ~(size_t)255; return r; };
  u16*   v_bf  = (u16*)  (w + alloc(4096UL*256*2));
  u16*   v_bt  = (u16*)  (w + alloc(2UL*256*2048*2));
  u16*   dxT   = (u16*)  (w + alloc(4UL*8192*256*2));
  u16*   dyT   = (u16*)  (w + alloc(4UL*8192*256*2));
  u16*   encT  = (u16*)  (w + alloc(256UL*32768*2));
  u16*   ct    = (u16*)  (w + alloc(2048UL*4096*2));
  u16*   st    = (u16*)  (w + alloc(2048UL*4096*2));
  float* t1    = (float*)(w + alloc(2UL*2048*256*4));
  u16*   xbuf  = (u16*)  (w + alloc((size_t)gc*33554432));
  u16*   scb   = (u16*)  (w + alloc((size_t)gc*8388608));
  float* abuf  = (float*)(w + alloc((size_t)gc*pv*2097152UL));
  float* part  = (float*)scb;                                  // alias: sc dead after g_pv
  u16*   lnAb  = (u16*)((char*)scb + (size_t)gc*ps*2097152UL); // alias, after part region
  u16*   roT   = (u16*)t1;                                     // alias: t1 dead after layers

  dim3 tb(32, 8);
  k_cossin<<<32768, 256, 0, stream>>>(ct, st);
  k_transpose<<<dim3(256, 8, 4),  tb, 0, stream>>>(dx,  dxT,  256,   8192, 256L*8192, 8192L*256);
  k_transpose<<<dim3(256, 8, 4),  tb, 0, stream>>>(dy,  dyT,  256,   8192, 256L*8192, 8192L*256);
  k_transpose<<<dim3(8, 1024, 1), tb, 0, stream>>>(enc, encT, 32768, 256,  0, 0);
  k_embed<<<4096, 256, 0, stream>>>(idx, wte, v_bf, v_bt);

  for (int l = 0; l < 6; ++l){
    for (int bh0 = 0; bh0 < 8; bh0 += gc){
      int ze = (8 - bh0 < gc) ? (8 - bh0) : gc;
      { GP g{}; g.bh0=bh0; g.A=v_bf; g.Bt=dxT; g.ct=ct; g.st=st; g.Cb=xbuf;
        g_rope<<<dim3(64,16,ze), 256, 0, stream>>>(g); }
      { GP g{}; g.bh0=bh0; g.A=xbuf; g.Cb=scb;
        g_qk<<<dim3(16,16,ze), 256, 0, stream>>>(g); }
      { GP g{}; g.bh0=bh0; g.A=scb; g.Bt=v_bt; g.Cf=abuf; g.zs=pvs; g.zm=pv-1;
        g_pv<<<dim3(2,16,ze*pv), 256, 0, stream>>>(g); }
      k_ln<<<ze*2048, 256, 0, stream>>>(abuf, lnAb, pv);
      { GP g{}; g.bh0=bh0; g.A=lnAb; g.Bt=dyT; g.A2=v_bf; g.Bt2=dxT; g.Y=xbuf;
        g_fuse<<<dim3(64,16,ze), 256, 0, stream>>>(g); }
      { GP g{}; g.bh0=bh0; g.A=xbuf; g.Bt=encT; g.Cf=part; g.zs=1; g.zm=1;
        g_enc<<<dim3(2,16,ze*ps), 256, 0, stream>>>(g); }
      k_acc<<<2048, 256, 0, stream>>>(part, t1, bh0, ze, ps);
    }
    k_finish<<<4096, 256, 0, stream>>>(t1, v_bf, v_bt);
  }
  k_transpose<<<dim3(8, 8, 1), tb, 0, stream>>>(ro, roT, 256, 256, 0, 0);
  { GP g{}; g.A=v_bf; g.Bt=roT; g.Cf=out;
    g_out<<<dim3(2,32,1), 256, 0, stream>>>(g); }
}